// Round 11
// baseline (204.728 us; speedup 1.0000x reference)
//
#include <hip/hip_runtime.h>
#include <hip/hip_bf16.h>

#define B_  4
#define L_  4096
#define DM  1024
#define DH  128
#define KS  4     // k-split for pv
#define QS  8     // q-split for stats

// (1/sqrt(128)) * log2(e): softmax computed in exp2 domain (exact same function).
// Q is PRE-SCALED by SC2 at projection epilogue; max-subtraction is dropped
// entirely (exp(s)/sum exp(s) == softmax exactly; s2 bounded, no overflow).
#define SC2 0.12752844f

typedef __bf16 bf16_t;
typedef __attribute__((ext_vector_type(8))) __bf16 bf16x8;
typedef __attribute__((ext_vector_type(4))) __bf16 bf16x4;
typedef __attribute__((ext_vector_type(4))) float f32x4;

#if __has_builtin(__builtin_amdgcn_exp2f)
#define EXP2F(x) __builtin_amdgcn_exp2f(x)
#else
#define EXP2F(x) exp2f(x)
#endif

__device__ __forceinline__ f32x4 mfma16(bf16x8 a, bf16x8 b, f32x4 c) {
    return __builtin_amdgcn_mfma_f32_16x16x32_bf16(a, b, c, 0, 0, 0);
}

// XOR swizzle on 16B slots within a row (row bytes 128 or 256)
__device__ __forceinline__ int swz(int row, int rowbytes, int colbyte) {
    int slot = colbyte >> 4;
    return row * rowbytes + (((slot ^ (row & 7)) << 4) | (colbyte & 15));
}

__device__ __forceinline__ bf16x8 cvt8v(f32x4 a, f32x4 b) {
    bf16x8 v;
    v[0] = (__bf16)a.x; v[1] = (__bf16)a.y; v[2] = (__bf16)a.z; v[3] = (__bf16)a.w;
    v[4] = (__bf16)b.x; v[5] = (__bf16)b.y; v[6] = (__bf16)b.z; v[7] = (__bf16)b.w;
    return v;
}

// async global->LDS, 16 B per lane. lds base must be wave-uniform; HW adds lane*16.
__device__ __forceinline__ void gload_lds16(const void* g, void* l) {
    __builtin_amdgcn_global_load_lds((const __attribute__((address_space(1))) void*)g,
                                     (__attribute__((address_space(3))) void*)l, 16, 0, 0);
}

// ---------------------------------------------------------------------------
// Kernel A0: W fp32 -> bf16 once.  Wb layout [3][DH][DM].  grid 192, block 256
// ---------------------------------------------------------------------------
__global__ __launch_bounds__(256) void wcvt_kernel(
    const float* __restrict__ Wq, const float* __restrict__ Wk, const float* __restrict__ Wv,
    bf16_t* __restrict__ Wb)
{
    int idx = (blockIdx.x * 256 + threadIdx.x) * 8;    // into [3][131072]
    int which = idx >> 17;
    int rem = idx & 131071;
    const float* W = which == 0 ? Wq : (which == 1 ? Wk : Wv);
    f32x4 a = *(const f32x4*)&W[rem];
    f32x4 b = *(const f32x4*)&W[rem + 4];
    *(bf16x8*)&Wb[idx] = cvt8v(a, b);
}

// ---------------------------------------------------------------------------
// Kernel A: contiguous-panel projections (R10 structure, observed ~88us floor).
// grid (512, 3), block 256.  Q output is pre-scaled by SC2.
// ---------------------------------------------------------------------------
__global__ __launch_bounds__(256) void projc_kernel(
    const float* __restrict__ Xq, const float* __restrict__ Xk, const float* __restrict__ Xv,
    const bf16_t* __restrict__ Wb,
    const float* __restrict__ bq, const float* __restrict__ bk, const float* __restrict__ bv,
    bf16_t* __restrict__ Q, bf16_t* __restrict__ K, bf16_t* __restrict__ V)
{
    const int which = blockIdx.y;
    const float* X    = which == 0 ? Xq : (which == 1 ? Xk : Xv);
    const float* bias = which == 0 ? bq : (which == 1 ? bk : bv);
    bf16_t*      O    = which == 0 ? Q  : (which == 1 ? K  : V);
    const bf16_t* Wm  = Wb + (size_t)which * DH * DM;
    const float  sc   = which == 0 ? SC2 : 1.0f;

    __shared__ bf16_t Xp[32 * 1024];    // 64 KB
    __shared__ bf16_t Wc[128 * 64];     // 16 KB

    const int tid  = threadIdx.x;
    const int lane = tid & 63;
    const int wave = tid >> 6;
    const int i16 = lane & 15, g4 = lane >> 4;
    const int row0 = blockIdx.x * 32;

    #pragma unroll
    for (int p = 0; p < 8; ++p) {
        int r = wave * 8 + p;
        const float* rowp = &X[(size_t)(row0 + r) * DM];
        #pragma unroll
        for (int h = 0; h < 2; ++h) {
            f32x4 a = *(const f32x4*)&rowp[h * 512 + lane * 8];
            f32x4 b = *(const f32x4*)&rowp[h * 512 + lane * 8 + 4];
            int s = h * 64 + lane;
            *(bf16x8*)((char*)Xp + r * 2048 + ((s ^ (r & 7)) << 4)) = cvt8v(a, b);
        }
    }

    f32x4 acc[2][2] = {};

    for (int t = 0; t < 16; ++t) {
        #pragma unroll
        for (int j = 0; j < 4; ++j) {
            int c = j * 4 + wave;
            int r = c * 8 + (lane >> 3);
            int s = lane & 7;
            gload_lds16(&Wm[(size_t)r * DM + t * 64 + ((s ^ (r & 7)) << 3)],
                        (char*)Wc + c * 1024);
        }
        __syncthreads();

        #pragma unroll
        for (int ks = 0; ks < 2; ++ks) {
            int q = t * 8 + ks * 4 + g4;
            bf16x8 af[2], wf[2];
            #pragma unroll
            for (int mi = 0; mi < 2; ++mi) {
                int r = mi * 16 + i16;
                af[mi] = *(const bf16x8*)((const char*)Xp + r * 2048 + ((q ^ (r & 7)) << 4));
            }
            #pragma unroll
            for (int ni = 0; ni < 2; ++ni) {
                int rw = wave * 32 + ni * 16 + i16;
                int tt = ks * 4 + g4;
                wf[ni] = *(const bf16x8*)((const char*)Wc + rw * 128 + ((tt ^ (rw & 7)) << 4));
            }
            #pragma unroll
            for (int mi = 0; mi < 2; ++mi)
                #pragma unroll
                for (int ni = 0; ni < 2; ++ni)
                    acc[mi][ni] = mfma16(af[mi], wf[ni], acc[mi][ni]);
        }
        __syncthreads();
    }

    #pragma unroll
    for (int ni = 0; ni < 2; ++ni) {
        int h = wave * 32 + ni * 16 + i16;
        float bb = bias[h];
        #pragma unroll
        for (int mi = 0; mi < 2; ++mi)
            #pragma unroll
            for (int j = 0; j < 4; ++j) {
                int r = row0 + mi * 16 + g4 * 4 + j;
                O[(size_t)r * DH + h] = (__bf16)((acc[mi][ni][j] + bb) * sc);
            }
    }
}

// ---------------------------------------------------------------------------
// Kernel B: column-sum-of-exp partial stats (NO max -- exact softmax algebra).
// grid (L/128=32, B, QS), block 256.  Per block: 128 k-cols x 512 q rows.
// K tile LDS-resident (32 KB); Q chunks of 128 through LDS (32 KB).
// ---------------------------------------------------------------------------
__global__ __launch_bounds__(256) void stats_kernel(
    const bf16_t* __restrict__ Q, const bf16_t* __restrict__ K,
    float* __restrict__ Lpart)
{
    const int b  = blockIdx.y;
    const int k0 = blockIdx.x * 128;
    const int qs = blockIdx.z;
    const int tid = threadIdx.x, lane = tid & 63, wave = tid >> 6;
    const int i16 = lane & 15, g4 = lane >> 4;

    __shared__ bf16_t Klds[128 * 128];   // 32 KB, rows 256 B swizzled
    __shared__ bf16_t Qlds[128 * 128];   // 32 KB

    const bf16_t* Kb = K + ((size_t)b * L_ + k0) * DH;
    #pragma unroll
    for (int it = 0; it < 8; ++it) {
        int id = it * 256 + tid;
        int r = id >> 4, s = id & 15;
        bf16x8 x = *(const bf16x8*)&Kb[(size_t)r * DH + s * 8];
        *(bf16x8*)((char*)Klds + swz(r, 256, s * 16)) = x;
    }

    float lrun[8];
    #pragma unroll
    for (int ni = 0; ni < 8; ++ni) lrun[ni] = 0.f;

    const bf16_t* Qb = Q + (size_t)b * L_ * DH;
    const int qbase = qs * (L_ / QS);
    for (int q0 = qbase; q0 < qbase + L_ / QS; q0 += 128) {
        __syncthreads();          // K visible (1st iter); prev Q reads done
        #pragma unroll
        for (int it = 0; it < 8; ++it) {
            int id = it * 256 + tid;
            int r = id >> 4, s = id & 15;
            bf16x8 x = *(const bf16x8*)&Qb[(size_t)(q0 + r) * DH + s * 8];
            *(bf16x8*)((char*)Qlds + swz(r, 256, s * 16)) = x;
        }
        __syncthreads();
        // wave w: q rows [w*32, w*32+32), all 128 k
        f32x4 st[2][8] = {};
        #pragma unroll
        for (int ds = 0; ds < 4; ++ds) {
            bf16x8 af[2];
            #pragma unroll
            for (int mi = 0; mi < 2; ++mi) {
                int r = wave * 32 + mi * 16 + i16;
                af[mi] = *(const bf16x8*)((const char*)Qlds + swz(r, 256, ds * 64 + g4 * 16));
            }
            #pragma unroll
            for (int ni = 0; ni < 8; ++ni) {
                int r = ni * 16 + i16;
                bf16x8 kf = *(const bf16x8*)((const char*)Klds + swz(r, 256, ds * 64 + g4 * 16));
                #pragma unroll
                for (int mi = 0; mi < 2; ++mi)
                    st[mi][ni] = mfma16(af[mi], kf, st[mi][ni]);
            }
        }
        // column sum of exp2 (k = ni*16 + (lane&15))
        #pragma unroll
        for (int ni = 0; ni < 8; ++ni) {
            float p = 0.f;
            #pragma unroll
            for (int mi = 0; mi < 2; ++mi)
                #pragma unroll
                for (int j = 0; j < 4; ++j)
                    p += EXP2F(st[mi][ni][j]);
            p += __shfl_xor(p, 16, 64);
            p += __shfl_xor(p, 32, 64);
            lrun[ni] += p;
        }
    }
    // cross-wave sum (each wave covered a disjoint q subset)
    __syncthreads();
    float* redl = (float*)Klds;       // 4*128 floats
    if (lane < 16) {
        #pragma unroll
        for (int ni = 0; ni < 8; ++ni)
            redl[wave * 128 + ni * 16 + lane] = lrun[ni];
    }
    __syncthreads();
    if (tid < 128) {
        float lt = redl[tid] + redl[128 + tid] + redl[256 + tid] + redl[384 + tid];
        Lpart[((size_t)qs * B_ + b) * L_ + k0 + tid] = lt;
    }
}

// ---------------------------------------------------------------------------
// Kernel B2: combine QS partial sums -> Lsum = 1/l.  grid (B*L/256), block 256
// ---------------------------------------------------------------------------
__global__ __launch_bounds__(256) void comb_kernel(
    const float* __restrict__ Lpart, float* __restrict__ Lsum)
{
    const size_t i = (size_t)blockIdx.x * 256 + threadIdx.x;
    const size_t N = (size_t)B_ * L_;
    float l = 0.f;
    #pragma unroll
    for (int qs = 0; qs < QS; ++qs) l += Lpart[qs * N + i];
    Lsum[i] = 1.0f / l;
}

// ---------------------------------------------------------------------------
// Kernel C: VT[b][v][k] = V[b][k][v] * recip_l[b][k]   (transpose + scale)
// grid (64, 2, 4), block 256
// ---------------------------------------------------------------------------
__global__ __launch_bounds__(256) void vt_kernel(
    const bf16_t* __restrict__ V, const float* __restrict__ Lsum, bf16_t* __restrict__ VT)
{
    const int b = blockIdx.z, v0 = blockIdx.y * 64, k0 = blockIdx.x * 64;
    __shared__ bf16_t tile[64][72];
    const int tid = threadIdx.x;
    const bf16_t* Vb = V + ((size_t)b * L_ + k0) * DH + v0;
    #pragma unroll
    for (int it = 0; it < 2; ++it) {
        int id = it * 256 + tid;
        int r = id >> 3, s = id & 7;
        bf16x8 x = *(const bf16x8*)&Vb[(size_t)r * DH + s * 8];
        *(bf16x8*)&tile[r][s * 8] = x;
    }
    __syncthreads();
    const int lane = tid & 63, wave = tid >> 6;
    float rl = Lsum[(size_t)b * L_ + k0 + lane];
    bf16_t* VTb = VT + ((size_t)b * DH + v0) * L_ + k0;
    #pragma unroll
    for (int i = 0; i < 16; ++i) {
        int v = wave * 16 + i;
        float x = (float)tile[lane][v];
        VTb[(size_t)v * L_ + lane] = (__bf16)(x * rl);
    }
}

// ---------------------------------------------------------------------------
// Kernel D: H[q,v] += sum_{k in range} exp2(s2[q,k]) * VT[v][k]
// grid (64, B, KS), block 256 (4 waves).  q-block 64, k-range 1024, chunks 128.
// No m2 (max dropped).  Partial k-sums additive -> fp32 atomicAdd.
// ---------------------------------------------------------------------------
__global__ __launch_bounds__(256) void pv_kernel(
    const bf16_t* __restrict__ Q, const bf16_t* __restrict__ K,
    const bf16_t* __restrict__ VT, float* __restrict__ out)
{
    const int b = blockIdx.y;
    const int q0 = blockIdx.x * 64;
    const int tid = threadIdx.x, lane = tid & 63, wave = tid >> 6;
    const int i16 = lane & 15, g4 = lane >> 4;

    __shared__ bf16_t QPlds[64 * 128];    // 16 KB: Q staging, then P tile [64 q][128 k]
    __shared__ bf16_t Klds[128 * 128];    // 32 KB
    __shared__ bf16_t VTlds[128 * 128];   // 32 KB

    const bf16_t* Qb = Q + ((size_t)b * L_ + q0) * DH;
    #pragma unroll
    for (int it = 0; it < 4; ++it) {
        int id = it * 256 + tid;
        int r = id >> 4, s = id & 15;
        bf16x8 x = *(const bf16x8*)&Qb[(size_t)r * DH + s * 8];
        *(bf16x8*)((char*)QPlds + swz(r, 256, s * 16)) = x;
    }
    __syncthreads();
    // resident Q fragments (B-operand of S^T): [ni = q 16-block][d-slice]
    bf16x8 qf[4][4];
    #pragma unroll
    for (int ni = 0; ni < 4; ++ni)
        #pragma unroll
        for (int ds = 0; ds < 4; ++ds) {
            int r = ni * 16 + i16;
            qf[ni][ds] = *(const bf16x8*)((const char*)QPlds + swz(r, 256, ds * 64 + g4 * 16));
        }

    f32x4 acc[4][2] = {};
    const bf16_t* Kb  = K  + (size_t)b * L_ * DH;
    const bf16_t* VTb = VT + (size_t)b * DH * L_;
    bf16_t* Plds = QPlds;                // alias: safe after qf loads + barrier

    const int kbase = blockIdx.z * (L_ / KS);
    for (int kc = kbase; kc < kbase + L_ / KS; kc += 128) {
        __syncthreads();   // prev chunk's K/VT/P reads done
        // stage K chunk [128 k][128 d]
        #pragma unroll
        for (int it = 0; it < 8; ++it) {
            int id = it * 256 + tid;
            int r = id >> 4, s = id & 15;
            bf16x8 x = *(const bf16x8*)&Kb[(size_t)(kc + r) * DH + s * 8];
            *(bf16x8*)((char*)Klds + swz(r, 256, s * 16)) = x;
        }
        // stage VT chunk [128 v][128 k]
        #pragma unroll
        for (int it = 0; it < 8; ++it) {
            int id = it * 256 + tid;
            int r = id >> 4, s = id & 15;
            bf16x8 x = *(const bf16x8*)&VTb[(size_t)r * L_ + kc + s * 8];
            *(bf16x8*)((char*)VTlds + swz(r, 256, s * 16)) = x;
        }
        __syncthreads();
        // S^T tile: wave owns k rows [w*32, w*32+32) (2 sub-tiles of 16), all 64 q
        f32x4 st[2][4] = {};
        #pragma unroll
        for (int ds = 0; ds < 4; ++ds) {
            bf16x8 kf[2];
            #pragma unroll
            for (int t = 0; t < 2; ++t) {
                int r = wave * 32 + t * 16 + i16;
                kf[t] = *(const bf16x8*)((const char*)Klds + swz(r, 256, ds * 64 + g4 * 16));
            }
            #pragma unroll
            for (int t = 0; t < 2; ++t)
                #pragma unroll
                for (int ni = 0; ni < 4; ++ni)
                    st[t][ni] = mfma16(kf[t], qf[ni][ds], st[t][ni]);
        }
        // P = exp2(st), bf16, into Plds [64 q][128 k] (rows 256 B)
        #pragma unroll
        for (int t = 0; t < 2; ++t)
            #pragma unroll
            for (int ni = 0; ni < 4; ++ni) {
                bf16x4 pk;
                pk[0] = (__bf16)EXP2F(st[t][ni][0]);
                pk[1] = (__bf16)EXP2F(st[t][ni][1]);
                pk[2] = (__bf16)EXP2F(st[t][ni][2]);
                pk[3] = (__bf16)EXP2F(st[t][ni][3]);
                int q = ni * 16 + i16;
                int colbyte = wave * 64 + t * 32 + g4 * 8;
                *(bf16x4*)((char*)Plds + swz(q, 256, colbyte)) = pk;
            }
        __syncthreads();
        // PV: wave owns v strip [w*32, w*32+32); 4 k-slices of 32
        #pragma unroll
        for (int ks = 0; ks < 4; ++ks) {
            bf16x8 pf[4], vf[2];
            #pragma unroll
            for (int mi = 0; mi < 4; ++mi) {
                int q = mi * 16 + i16;
                pf[mi] = *(const bf16x8*)((const char*)Plds + swz(q, 256, ks * 64 + g4 * 16));
            }
            #pragma unroll
            for (int ni = 0; ni < 2; ++ni) {
                int v = wave * 32 + ni * 16 + i16;
                vf[ni] = *(const bf16x8*)((const char*)VTlds + swz(v, 256, ks * 64 + g4 * 16));
            }
            #pragma unroll
            for (int mi = 0; mi < 4; ++mi)
                #pragma unroll
                for (int ni = 0; ni < 2; ++ni)
                    acc[mi][ni] = mfma16(pf[mi], vf[ni], acc[mi][ni]);
        }
    }
    // epilogue: fp32 atomic accumulate (KS blocks contribute per output)
    #pragma unroll
    for (int mi = 0; mi < 4; ++mi)
        #pragma unroll
        for (int ni = 0; ni < 2; ++ni)
            #pragma unroll
            for (int j = 0; j < 4; ++j) {
                int q = q0 + mi * 16 + g4 * 4 + j;
                int v = wave * 32 + ni * 16 + i16;
                atomicAdd(&out[((size_t)b * L_ + q) * DH + v], acc[mi][ni][j]);
            }
}

// ---------------------------------------------------------------------------
extern "C" void kernel_launch(void* const* d_in, const int* in_sizes, int n_in,
                              void* d_out, int out_size, void* d_ws, size_t ws_size,
                              hipStream_t stream)
{
    const float* inq = (const float*)d_in[0];
    const float* ink = (const float*)d_in[1];
    const float* inv = (const float*)d_in[2];
    const float* Wq  = (const float*)d_in[3];
    const float* bq  = (const float*)d_in[4];
    const float* Wk  = (const float*)d_in[5];
    const float* bk  = (const float*)d_in[6];
    const float* Wv  = (const float*)d_in[7];
    const float* bv  = (const float*)d_in[8];
    float* out = (float*)d_out;

    const size_t nQKV = (size_t)B_ * L_ * DH;   // 2,097,152 elements
    const size_t nBL  = (size_t)B_ * L_;
    char* ws = (char*)d_ws;
    bf16_t* Q  = (bf16_t*)ws;
    bf16_t* K  = Q + nQKV;
    bf16_t* V  = K + nQKV;
    bf16_t* VT = V + nQKV;
    float*  Lsum  = (float*)(VT + nQKV);
    float*  Lpart = Lsum + nBL;          // QS * B*L
    // Wb (768 KB) aliases VT: live only during wcvt+projc; VT written later.
    bf16_t* Wbuf = VT;

    (void)hipMemsetAsync(out, 0, nQKV * sizeof(float), stream);
    wcvt_kernel<<<dim3(192), 256, 0, stream>>>(Wq, Wk, Wv, Wbuf);
    projc_kernel<<<dim3(512, 3), 256, 0, stream>>>(inq, ink, inv, Wbuf, bq, bk, bv, Q, K, V);
    stats_kernel<<<dim3(L_ / 128, B_, QS), 256, 0, stream>>>(Q, K, Lpart);
    comb_kernel<<<dim3(nBL / 256), 256, 0, stream>>>(Lpart, Lsum);
    vt_kernel<<<dim3(L_ / 64, DH / 64, B_), 256, 0, stream>>>(V, Lsum, VT);
    pv_kernel<<<dim3(L_ / 64, B_, KS), 256, 0, stream>>>(Q, K, VT, out);
}